// Round 11
// baseline (157.976 us; speedup 1.0000x reference)
//
#include <hip/hip_runtime.h>
#include <stdint.h>

#define BATCH 4
#define SEQ   2048
#define FDIM  512
#define NHEAD 8
#define HDIM  64
#define KNN   32

typedef unsigned int u32;
typedef unsigned long long u64;
typedef unsigned short u16;
typedef unsigned short bf16_t;

typedef __attribute__((ext_vector_type(8))) short short8;   // 8 bf16 = 4 VGPRs
typedef __attribute__((ext_vector_type(4))) float f32x4;

#define SF  ((size_t)SEQ * FDIM)            // 1,048,576 per-batch elements
#define BSF ((size_t)BATCH * SF)            // 4,194,304

// fused_ck: 10752 blocks, interleaved bid%21: r<5 -> cast/xpart (512*5=2560),
// r>=5 -> knn (512*16=8192). r10-validated (157.5 µs).
#define CAST_NB 2432                        // 2048 (x) + 3*128 (weights)
#define FUSED_NB 10752

__device__ __forceinline__ bf16_t f2bf(float f) {
    u32 x = __float_as_uint(f);
    return (bf16_t)((x + 0x7FFFu + ((x >> 16) & 1u)) >> 16);   // RNE
}
__device__ __forceinline__ float bf2f(bf16_t u) { return __uint_as_float(((u32)u) << 16); }
__device__ __forceinline__ void bf2x2(u32 p, float& a, float& b) {
    a = __uint_as_float(p << 16);          // element 2i (low u16)
    b = __uint_as_float(p & 0xFFFF0000u);  // element 2i+1 (high u16)
}
__device__ __forceinline__ u64 min_u64(u64 a, u64 b) { return a < b ? a : b; }
__device__ __forceinline__ u64 shfl_xor_u64(u64 v, int m) {
    int lo = __shfl_xor((int)(u32)v, m, 64);
    int hi = __shfl_xor((int)(u32)(v >> 32), m, 64);
    return (((u64)(u32)hi) << 32) | (u32)lo;
}

// async global->LDS, 16B per lane (HW: wave-uniform LDS base + lane*16)
__device__ __forceinline__ void gld16(const bf16_t* gp, bf16_t* lp) {
    __builtin_amdgcn_global_load_lds(
        (const __attribute__((address_space(1))) u32*)gp,
        (__attribute__((address_space(3))) u32*)lp, 16, 0, 0);
}

// DPP lane permute (VALU pipe, no LDS). HW-validated rounds 2-10 (passed).
template <int CTRL>
__device__ __forceinline__ float dppf(float x) {
    return __int_as_float(__builtin_amdgcn_update_dpp(
        0, __float_as_int(x), CTRL, 0xF, 0xF, true));
}

// dot of 8 bf16 (packed in uint4) with 8 fp32 q values
__device__ __forceinline__ float dot8(uint4 k, f32x4 qa, f32x4 qb) {
    float f0, f1, f2, f3, f4, f5, f6, f7;
    bf2x2(k.x, f0, f1); bf2x2(k.y, f2, f3);
    bf2x2(k.z, f4, f5); bf2x2(k.w, f6, f7);
    return qa.x * f0 + qa.y * f1 + qa.z * f2 + qa.w * f3
         + qb.x * f4 + qb.y * f5 + qb.z * f6 + qb.w * f7;
}

// o[0..7] += w * unpack(v)
__device__ __forceinline__ void acc8(uint4 v, float w, float* o) {
    float f0, f1, f2, f3, f4, f5, f6, f7;
    bf2x2(v.x, f0, f1); bf2x2(v.y, f2, f3);
    bf2x2(v.z, f4, f5); bf2x2(v.w, f6, f7);
    o[0] += w * f0; o[1] += w * f1; o[2] += w * f2; o[3] += w * f3;
    o[4] += w * f4; o[5] += w * f5; o[6] += w * f6; o[7] += w * f7;
}

// ---------------------------------------------------------------------------
// cast body: fp32 -> bf16, 8 elem/thread. Linear block id selects tensor.
// ---------------------------------------------------------------------------
__device__ __forceinline__ void cast_body(int cid,
                                          const float* __restrict__ x,
                                          const float* __restrict__ wq,
                                          const float* __restrict__ wk,
                                          const float* __restrict__ wv,
                                          bf16_t* __restrict__ xb,
                                          bf16_t* __restrict__ wqb,
                                          bf16_t* __restrict__ wkb,
                                          bf16_t* __restrict__ wvb) {
    int z, blk;
    if (cid < 2048) { z = 0; blk = cid; }
    else { int d = cid - 2048; z = 1 + (d >> 7); blk = d & 127; }
    const float* src = (z == 0) ? x : (z == 1) ? wq : (z == 2) ? wk : wv;
    bf16_t* dst      = (z == 0) ? xb : (z == 1) ? wqb : (z == 2) ? wkb : wvb;
    size_t idx = (size_t)blk * 256 + threadIdx.x;
    const float4 a = ((const float4*)src)[idx * 2 + 0];
    const float4 b = ((const float4*)src)[idx * 2 + 1];
    uint4 o;
    o.x = (u32)f2bf(a.x) | ((u32)f2bf(a.y) << 16);
    o.y = (u32)f2bf(a.z) | ((u32)f2bf(a.w) << 16);
    o.z = (u32)f2bf(b.x) | ((u32)f2bf(b.y) << 16);
    o.w = (u32)f2bf(b.z) | ((u32)f2bf(b.w) << 16);
    ((uint4*)dst)[idx] = o;
}

// ---------------------------------------------------------------------------
// xpart body: per-(batch,chunk) partial column-mean of x -> xpart slot.
// ---------------------------------------------------------------------------
__device__ __forceinline__ void xpart_body(int id, const float* __restrict__ x,
                                           float* __restrict__ xpart) {
    const int b = id >> 5, chunk = id & 31;
    const int tid = threadIdx.x;
    const float* xp = x + (size_t)b * SF + (size_t)chunk * 64 * FDIM;
    float s0 = 0.f, s1 = 0.f;
    for (int r = 0; r < 64; ++r) {
        s0 += xp[(size_t)r * FDIM + tid];
        s1 += xp[(size_t)r * FDIM + tid + 256];
    }
    float* dst = xpart + (size_t)id * FDIM;
    dst[tid]       = s0 * (1.f / 2048.f);
    dst[tid + 256] = s1 * (1.f / 2048.f);
}

// ---------------------------------------------------------------------------
// kNN body (HW-validated r14 BLOCK version): exact SET selection via
// two-level histogram. 256 threads, 8 candidates/thread, 6 barriers.
// ---------------------------------------------------------------------------
__device__ __forceinline__ void knn_body(char* smem, int blk,
                                         const float* __restrict__ coords,
                                         u16* __restrict__ nn_out) {
    u32* chist = (u32*)smem;                  // 64  u32
    u32* fhist = (u32*)(smem + 256);          // 256 u32
    u64* bk    = (u64*)(smem + 1280);         // 64  u64
    u64* wpart = (u64*)(smem + 1792);         // 4   u64
    u32* sc    = (u32*)(smem + 1824);         // 8   u32
    const int b   = blk >> 11;
    const int qi  = blk & (SEQ - 1);
    const int t   = threadIdx.x;
    const int wid = t >> 6, lane = t & 63;
    const size_t qb = (size_t)blk * KNN;

    fhist[t & 255] = 0;
    if (t < 64) chist[t] = 0;
    if (t == 0) { sc[2] = 0; sc[3] = 0; }

    const float* cb = coords + (size_t)b * SEQ * 3;
    const float qx = cb[qi * 3 + 0];
    const float qy = cb[qi * 3 + 1];
    const float qz = cb[qi * 3 + 2];

    float dist[8];
    int   ib[8];
    u64 tmin = ~0ull;
#pragma unroll
    for (int i = 0; i < 8; ++i) {
        int c = i * 256 + t;
        float dx = __fsub_rn(cb[c * 3 + 0], qx);
        float dy = __fsub_rn(cb[c * 3 + 1], qy);
        float dz = __fsub_rn(cb[c * 3 + 2], qz);
        // numpy order: (dx*dx + dy*dy) + dz*dz, no FMA, IEEE sqrt
        float d2 = __fadd_rn(__fadd_rn(__fmul_rn(dx, dx), __fmul_rn(dy, dy)),
                             __fmul_rn(dz, dz));
        dist[i] = __fsqrt_rn(d2);
        ib[i] = (int)(dist[i] * 8192.0f);
        u64 key = (((u64)__float_as_uint(dist[i])) << 32) | (u32)c;
        tmin = min_u64(tmin, key);
    }
    tmin = min_u64(tmin, shfl_xor_u64(tmin, 1));
    tmin = min_u64(tmin, shfl_xor_u64(tmin, 2));
    tmin = min_u64(tmin, shfl_xor_u64(tmin, 4));
    tmin = min_u64(tmin, shfl_xor_u64(tmin, 8));
    tmin = min_u64(tmin, shfl_xor_u64(tmin, 16));
    tmin = min_u64(tmin, shfl_xor_u64(tmin, 32));
    if (lane == 0) wpart[wid] = tmin;
    __syncthreads();                                  // B1

#pragma unroll
    for (int i = 0; i < 8; ++i) atomicAdd(&chist[ib[i] >> 8], 1u);
    const u64 M = min_u64(min_u64(wpart[0], wpart[1]),
                          min_u64(wpart[2], wpart[3]));
    __syncthreads();                                  // B2

    if (t < 64) {
        u32 h = chist[t];
        u32 cum = h;
#pragma unroll
        for (int d = 1; d < 64; d <<= 1) {
            u32 v = (u32)__shfl_up((int)cum, d, 64);
            if (t >= d) cum += v;
        }
        u64 bal = __ballot(cum >= 33);
        int Bc = __ffsll((long long)bal) - 1;
        u32 excl = cum - h;
        u32 base = (u32)__shfl((int)excl, Bc, 64);
        if (t == 0) { sc[0] = (u32)Bc; sc[1] = base; }
    }
    __syncthreads();                                  // B3

    {
        const int Bc = (int)sc[0];
#pragma unroll
        for (int i = 0; i < 8; ++i)
            if ((ib[i] >> 8) == Bc) atomicAdd(&fhist[ib[i] & 255], 1u);
    }
    __syncthreads();                                  // B4

    if (t < 64) {
        const u32 Bc = sc[0], base = sc[1];
        u32 f0 = fhist[t * 4 + 0], f1 = fhist[t * 4 + 1];
        u32 f2 = fhist[t * 4 + 2], f3 = fhist[t * 4 + 3];
        u32 s = f0 + f1 + f2 + f3;
        u32 cum = s;
#pragma unroll
        for (int d = 1; d < 64; d <<= 1) {
            u32 v = (u32)__shfl_up((int)cum, d, 64);
            if (t >= d) cum += v;
        }
        u32 E = base + (cum - s);
        u32 c0 = E + f0, c1 = c0 + f1, c2 = c1 + f2, c3 = c2 + f3;
        u64 bal = __ballot(c3 >= 33);
        int L = __ffsll((long long)bal) - 1;
        if (t == L) {
            int j = (c0 >= 33) ? 0 : (c1 >= 33) ? 1 : (c2 >= 33) ? 2 : 3;
            sc[4] = (Bc << 8) | (u32)(t * 4 + j);     // IBT
        }
    }
    __syncthreads();                                  // B5

    {
        const int ibt = (int)sc[4];
#pragma unroll
        for (int i = 0; i < 8; ++i) {
            int c = i * 256 + t;
            u64 key = (((u64)__float_as_uint(dist[i])) << 32) | (u32)c;
            if (ib[i] < ibt) {
                if (key != M) {
                    u32 pos = atomicAdd(&sc[2], 1u);
                    nn_out[qb + pos] = (u16)c;
                }
            } else if (ib[i] == ibt) {
                u32 bp = atomicAdd(&sc[3], 1u);
                if (bp < 64) bk[bp] = key;
            }
        }
    }
    __syncthreads();                                  // B6

    if (t < 64) {
        const u32 m = sc[2];
        const int n = (int)min(sc[3], 64u);
        const int need = 32 - (int)m;
        u64 k = (t < n) ? bk[t] : ~0ull;
        if (k == M) k = ~0ull;
#pragma unroll 1
        for (int r = 0; r < need; ++r) {
            u64 g = k;
            g = min_u64(g, shfl_xor_u64(g, 1));
            g = min_u64(g, shfl_xor_u64(g, 2));
            g = min_u64(g, shfl_xor_u64(g, 4));
            g = min_u64(g, shfl_xor_u64(g, 8));
            g = min_u64(g, shfl_xor_u64(g, 16));
            g = min_u64(g, shfl_xor_u64(g, 32));
            if (k == g) {
                nn_out[qb + m + r] = (u16)(g & 0x7FF);
                k = ~0ull;
            }
        }
    }
}

// ---------------------------------------------------------------------------
// Dispatch 1: cast + xpart + knn, INTERLEAVED (r10-validated).
// ---------------------------------------------------------------------------
__global__ __launch_bounds__(256) void fused_ck(const float* __restrict__ x,
                                                const float* __restrict__ wq,
                                                const float* __restrict__ wk,
                                                const float* __restrict__ wv,
                                                bf16_t* __restrict__ xb,
                                                bf16_t* __restrict__ wqb,
                                                bf16_t* __restrict__ wkb,
                                                bf16_t* __restrict__ wvb,
                                                const float* __restrict__ coords,
                                                u16* __restrict__ nn_out,
                                                float* __restrict__ xpart) {
    __shared__ __align__(16) char smem[1856];   // knn scratch only
    const int bid = blockIdx.x;
    const int g = bid / 21, r = bid - g * 21;
    if (r < 5) {
        const int a = g * 5 + r;                // 0..2559
        if (a < CAST_NB) cast_body(a, x, wq, wk, wv, xb, wqb, wkb, wvb);
        else             xpart_body(a - CAST_NB, x, xpart);
    } else {
        knn_body(smem, g * 16 + (r - 5), coords, nn_out);
    }
}

// ---------------------------------------------------------------------------
// Dispatch 2: GEMM + metric tail (z==3). NEW (r11): 2-phase double-buffered
// LDS (T3-minimum recipe) — stage tile t+1 BEFORE computing tile t, so the
// global_load_lds latency hides under the MFMA phase; ONE barrier per K-step
// (was: stage -> vmcnt(0) -> barrier -> compute, fully exposed latency).
// Race-safe: end-of-iter vmcnt(0)+barrier guarantees (a) staged buf ready,
// (b) all ds_reads of the compute buf done before it's overwritten next iter.
// ---------------------------------------------------------------------------
__global__ __launch_bounds__(256) void gemm_mfma(const bf16_t* __restrict__ xb,
                                                 const bf16_t* __restrict__ wqb,
                                                 const bf16_t* __restrict__ wkb,
                                                 const bf16_t* __restrict__ wvb,
                                                 bf16_t* __restrict__ qkv,
                                                 const float* __restrict__ xpart,
                                                 const float* __restrict__ Wkf,
                                                 float* __restrict__ metric) {
    __shared__ __align__(16) bf16_t As[2][128 * 32];   // 16 KB
    __shared__ __align__(16) bf16_t Bs[2][128 * 32];   // 16 KB
    const int z = blockIdx.z;
    const int tid  = threadIdx.x;

    if (z == 3) {                         // ---- metric tail ----
        const int id = blockIdx.y * 4 + blockIdx.x;    // 0..255
        if (id >= 8) return;
        float* xbarL = (float*)&As[0][0];
        const int b = id >> 1;
        float a0 = 0.f, a1 = 0.f;
#pragma unroll 4
        for (int c = 0; c < 32; ++c) {
            const float* xp = xpart + (size_t)((b << 5) | c) * FDIM;
            a0 += xp[tid];
            a1 += xp[tid + 256];
        }
        xbarL[tid] = a0; xbarL[tid + 256] = a1;
        __syncthreads();
        const int f = ((id & 1) << 8) | tid;
        const float* wr = Wkf + (size_t)f * FDIM;
        float acc = 0.f;
#pragma unroll 4
        for (int kk = 0; kk < FDIM; kk += 4) {
            float4 wv = *(const float4*)(wr + kk);
            acc += xbarL[kk + 0] * wv.x + xbarL[kk + 1] * wv.y
                 + xbarL[kk + 2] * wv.z + xbarL[kk + 3] * wv.w;
        }
        metric[(b << 9) | f] = acc;
        return;
    }

    // z: 0 -> Q (slab 2), 1 -> K (slab 0), 2 -> V (slab 1)
    const bf16_t* W = (z == 0) ? wqb : (z == 1) ? wkb : wvb;
    const int slab  = (z == 0) ? 2 : (z - 1);
    const int wid  = tid >> 6, lane = tid & 63;
    const int m16  = lane & 15, quad = lane >> 4;
    const int wm   = (wid & 1) * 64;
    const int wn   = (wid >> 1) * 64;
    const int m0   = blockIdx.y * 128;
    const int n0   = blockIdx.x * 128;

    const int sr = tid >> 2, sc = (tid & 3) * 8;
    const bf16_t* agp = xb + (size_t)(m0 + sr) * FDIM + sc;
    const bf16_t* bgp = W  + (size_t)(n0 + sr) * FDIM + sc;
    const int l0 = tid * 8;              // this thread's 16B LDS slot

    f32x4 acc[4][4];
#pragma unroll
    for (int i = 0; i < 4; ++i)
#pragma unroll
        for (int j = 0; j < 4; ++j) acc[i][j] = (f32x4){0.f, 0.f, 0.f, 0.f};

    // prologue: stage k0=0 into buf 0
    gld16(agp,                      &As[0][l0]);
    gld16(agp + (size_t)64 * FDIM,  &As[0][l0 + 2048]);
    gld16(bgp,                      &Bs[0][l0]);
    gld16(bgp + (size_t)64 * FDIM,  &Bs[0][l0 + 2048]);
    __asm__ volatile("s_waitcnt vmcnt(0)" ::: "memory");
    __syncthreads();

    int cur = 0;
#pragma unroll 1
    for (int k0 = 0; k0 < FDIM; k0 += 32) {
        const int nxt = cur ^ 1;
        if (k0 + 32 < FDIM) {            // stage NEXT tile (overlaps compute)
            gld16(agp + k0 + 32,                      &As[nxt][l0]);
            gld16(agp + (size_t)64 * FDIM + k0 + 32,  &As[nxt][l0 + 2048]);
            gld16(bgp + k0 + 32,                      &Bs[nxt][l0]);
            gld16(bgp + (size_t)64 * FDIM + k0 + 32,  &Bs[nxt][l0 + 2048]);
        }

        short8 af[4], bfr[4];
#pragma unroll
        for (int i = 0; i < 4; ++i)
            af[i] = *(const short8*)(&As[cur][(wm + i * 16 + m16) * 32 + quad * 8]);
#pragma unroll
        for (int j = 0; j < 4; ++j)
            bfr[j] = *(const short8*)(&Bs[cur][(wn + j * 16 + m16) * 32 + quad * 8]);
#pragma unroll
        for (int i = 0; i < 4; ++i)
#pragma unroll
            for (int j = 0; j < 4; ++j)
                acc[i][j] = __builtin_amdgcn_mfma_f32_16x16x32_bf16(af[i], bfr[j],
                                                                    acc[i][j], 0, 0, 0);

        __asm__ volatile("s_waitcnt vmcnt(0)" ::: "memory");
        __syncthreads();
        cur = nxt;
    }

    bf16_t* base = qkv + (size_t)slab * BSF;
#pragma unroll
    for (int i = 0; i < 4; ++i) {
        const int rowb = m0 + wm + i * 16 + quad * 4;
#pragma unroll
        for (int r = 0; r < 4; ++r) {
            bf16_t* orow = base + (size_t)(rowb + r) * FDIM + n0 + wn + m16;
            orow[ 0] = f2bf(acc[i][0][r]); orow[16] = f2bf(acc[i][1][r]);
            orow[32] = f2bf(acc[i][2][r]); orow[48] = f2bf(acc[i][3][r]);
        }
    }
}

// ---------------------------------------------------------------------------
// Dispatch 3: Attention v7 (r9/r10-validated) — cooperative gather + direct
// bf16 q load, __launch_bounds__(256, 8). Unchanged.
// ---------------------------------------------------------------------------
__global__ __launch_bounds__(256, 8) void attn_kernel(const bf16_t* __restrict__ qkv,
                                                      const u16* __restrict__ nn,
                                                      float* __restrict__ out) {
    __shared__ float osl[4][8][64];                       // 8 KB: o partials
    const int i   = blockIdx.x;                           // 0..16383
    const int b   = (i & 7) >> 1;                         // XCD pair -> batch
    const int jb  = ((i >> 3) << 1) | (i & 1);            // 0..4095, bijective
    const int tid = threadIdx.x;
    const int wid = tid >> 6, lane = tid & 63;
    const int gid = (jb << 2) | wid;                      // 0..16383 per batch
    const int qi  = gid >> 3, h = gid & 7;
    const int blk = (b << 11) | qi;

    int sreg = 0;
    if (lane < KNN) sreg = (int)nn[(size_t)blk * KNN + lane] & (SEQ - 1);

    const int g3 = lane >> 3, l8 = lane & 7;
    const int r0 = __shfl(sreg,      g3, 64);
    const int r1 = __shfl(sreg,  8 + g3, 64);
    const int r2 = __shfl(sreg, 16 + g3, 64);
    const int r3 = __shfl(sreg, 24 + g3, 64);

    // q: bf16 slab 2, this lane's 8 dims (uniform across g3 -> L1 broadcast)
    const uint4 qw = *(const uint4*)(qkv + 2 * BSF + (size_t)blk * FDIM
                                     + h * HDIM + l8 * 8);

    const bf16_t* base = qkv + ((size_t)(b << 11)) * FDIM + h * HDIM + l8 * 8;
    const uint4 k0 = *(const uint4*)(base + (size_t)r0 * FDIM);
    const uint4 k1 = *(const uint4*)(base + (size_t)r1 * FDIM);
    const uint4 k2 = *(const uint4*)(base + (size_t)r2 * FDIM);
    const uint4 k3 = *(const uint4*)(base + (size_t)r3 * FDIM);
    const uint4 v0 = *(const uint4*)(base + BSF + (size_t)r0 * FDIM);
    const uint4 v1 = *(const uint4*)(base + BSF + (size_t)r1 * FDIM);
    const uint4 v2 = *(const uint4*)(base + BSF + (size_t)r2 * FDIM);
    const uint4 v3 = *(const uint4*)(base + BSF + (size_t)r3 * FDIM);

    float q0, q1, q2, q3, q4, q5, q6, q7;
    bf2x2(qw.x, q0, q1); bf2x2(qw.y, q2, q3);
    bf2x2(qw.z, q4, q5); bf2x2(qw.w, q6, q7);
    const f32x4 qa = {q0, q1, q2, q3};
    const f32x4 qb = {q4, q5, q6, q7};

    // QK^T: per-lane partial dot (8 dims), then 3-step DPP tree over the
    // 8-lane group -> s uniform across the group.
    float s0 = dot8(k0, qa, qb);
    float s1 = dot8(k1, qa, qb);
    float s2 = dot8(k2, qa, qb);
    float s3 = dot8(k3, qa, qb);
    s0 += dppf<0xB1>(s0); s0 += dppf<0x4E>(s0); s0 += dppf<0x141>(s0);
    s1 += dppf<0xB1>(s1); s1 += dppf<0x4E>(s1); s1 += dppf<0x141>(s1);
    s2 += dppf<0xB1>(s2); s2 += dppf<0x4E>(s2); s2 += dppf<0x141>(s2);
    s3 += dppf<0xB1>(s3); s3 += dppf<0x4E>(s3); s3 += dppf<0x141>(s3);
    s0 *= 0.125f; s1 *= 0.125f; s2 *= 0.125f; s3 *= 0.125f;   // 1/sqrt(64)

    // softmax over 32 rows: per-lane 4 values, uniform within 8-groups.
    float ml = fmaxf(fmaxf(s0, s1), fmaxf(s2, s3));
    ml = fmaxf(ml, dppf<0x140>(ml));              // bit3 (uniform-in-8 safe)
    ml = fmaxf(ml, __shfl_xor(ml, 16, 64));
    ml = fmaxf(ml, __shfl_xor(ml, 32, 64));
    const float e0 = __expf(s0 - ml), e1 = __expf(s1 - ml);
    const float e2 = __expf(s2 - ml), e3 = __expf(s3 - ml);
    float sl = (e0 + e1) + (e2 + e3);
    sl += dppf<0x140>(sl);
    sl += __shfl_xor(sl, 16, 64);
    sl += __shfl_xor(sl, 32, 64);
    const float rs = 1.0f / sl;
    const float w0 = e0 * rs, w1 = e1 * rs, w2 = e2 * rs, w3 = e3 * rs;

    // PV: weights lane-local, V rows identical to K rows.
    float o[8] = {0.f, 0.f, 0.f, 0.f, 0.f, 0.f, 0.f, 0.f};
    acc8(v0, w0, o);
    acc8(v1, w1, o);
    acc8(v2, w2, o);
    acc8(v3, w3, o);

    // cross-group reduce (8 groups) via LDS, then coalesced store.
    *(f32x4*)&osl[wid][g3][l8 * 8]     = (f32x4){o[0], o[1], o[2], o[3]};
    *(f32x4*)&osl[wid][g3][l8 * 8 + 4] = (f32x4){o[4], o[5], o[6], o[7]};
    __asm__ volatile("s_waitcnt lgkmcnt(0)" ::: "memory");
    __builtin_amdgcn_wave_barrier();
    float r = osl[wid][0][lane];
#pragma unroll
    for (int g = 1; g < 8; ++g) r += osl[wid][g][lane];
    out[(size_t)blk * FDIM + h * HDIM + lane] = r;
}

// ---------------------------------------------------------------------------
extern "C" void kernel_launch(void* const* d_in, const int* in_sizes, int n_in,
                              void* d_out, int out_size, void* d_ws, size_t ws_size,
                              hipStream_t stream) {
    const float* x      = (const float*)d_in[0];
    const float* coords = (const float*)d_in[1];
    const float* Wq     = (const float*)d_in[2];
    const float* Wk     = (const float*)d_in[3];
    const float* Wv     = (const float*)d_in[4];
    float* out    = (float*)d_out;
    float* metric = out + BSF;

    // ws layout (~34.3 MiB):
    //   xb bf16 BSF (8 MiB) | wqb/wkb/wvb bf16 (1.5 MiB) | qkv bf16 3*BSF
    //   (24 MiB: K,V,Q slabs) | nn u16 (0.5 MiB) | xpart f32 (256 KiB)
    char* p = (char*)d_ws;
    bf16_t* xb    = (bf16_t*)p;                      p += BSF * sizeof(bf16_t);
    bf16_t* wqb   = (bf16_t*)p;                      p += (size_t)FDIM * FDIM * sizeof(bf16_t);
    bf16_t* wkb   = (bf16_t*)p;                      p += (size_t)FDIM * FDIM * sizeof(bf16_t);
    bf16_t* wvb   = (bf16_t*)p;                      p += (size_t)FDIM * FDIM * sizeof(bf16_t);
    bf16_t* qkv   = (bf16_t*)p;                      p += 3 * BSF * sizeof(bf16_t);
    u16*    nn    = (u16*)p;                         p += (size_t)BATCH * SEQ * KNN * sizeof(u16);
    float*  xpart = (float*)p;

    // 1) cast + xpart + knn, interleaved
    fused_ck<<<FUSED_NB, 256, 0, stream>>>(
        x, Wq, Wk, Wv, xb, wqb, wkb, wvb, coords, nn, xpart);

    // 2) gemm (q/k/v -> ws bf16 slabs) + metric tail (z==3)
    gemm_mfma<<<dim3(FDIM / 128, (BATCH * SEQ) / 128, 4), 256, 0, stream>>>(
        xb, wqb, wkb, wvb, qkv, xpart, Wk, metric);

    // 3) attention
    attn_kernel<<<BATCH * SEQ * NHEAD / 4, 256, 0, stream>>>(qkv, nn, out);
}

// Round 12
// 157.036 us; speedup vs baseline: 1.0060x; 1.0060x over previous
//
#include <hip/hip_runtime.h>
#include <stdint.h>

#define BATCH 4
#define SEQ   2048
#define FDIM  512
#define NHEAD 8
#define HDIM  64
#define KNN   32

typedef unsigned int u32;
typedef unsigned long long u64;
typedef unsigned short u16;
typedef unsigned short bf16_t;

typedef __attribute__((ext_vector_type(8))) short short8;   // 8 bf16 = 4 VGPRs
typedef __attribute__((ext_vector_type(4))) float f32x4;

#define SF  ((size_t)SEQ * FDIM)            // 1,048,576 per-batch elements
#define BSF ((size_t)BATCH * SF)            // 4,194,304

// fused_ck: 10752 blocks, interleaved bid%21: r<5 -> cast/xpart (512*5=2560),
// r>=5 -> knn (512*16=8192). r10-validated (157.5 µs).
#define CAST_NB 2432                        // 2048 (x) + 3*128 (weights)
#define FUSED_NB 10752

__device__ __forceinline__ bf16_t f2bf(float f) {
    u32 x = __float_as_uint(f);
    return (bf16_t)((x + 0x7FFFu + ((x >> 16) & 1u)) >> 16);   // RNE
}
__device__ __forceinline__ float bf2f(bf16_t u) { return __uint_as_float(((u32)u) << 16); }
__device__ __forceinline__ void bf2x2(u32 p, float& a, float& b) {
    a = __uint_as_float(p << 16);          // element 2i (low u16)
    b = __uint_as_float(p & 0xFFFF0000u);  // element 2i+1 (high u16)
}
__device__ __forceinline__ u64 min_u64(u64 a, u64 b) { return a < b ? a : b; }
__device__ __forceinline__ u64 shfl_xor_u64(u64 v, int m) {
    int lo = __shfl_xor((int)(u32)v, m, 64);
    int hi = __shfl_xor((int)(u32)(v >> 32), m, 64);
    return (((u64)(u32)hi) << 32) | (u32)lo;
}

// async global->LDS, 16B per lane (HW: wave-uniform LDS base + lane*16)
__device__ __forceinline__ void gld16(const bf16_t* gp, bf16_t* lp) {
    __builtin_amdgcn_global_load_lds(
        (const __attribute__((address_space(1))) u32*)gp,
        (__attribute__((address_space(3))) u32*)lp, 16, 0, 0);
}

// DPP lane permute (VALU pipe, no LDS). HW-validated rounds 2-11 (passed).
template <int CTRL>
__device__ __forceinline__ float dppf(float x) {
    return __int_as_float(__builtin_amdgcn_update_dpp(
        0, __float_as_int(x), CTRL, 0xF, 0xF, true));
}

// dot of 8 bf16 (packed in uint4) with 8 fp32 q values
__device__ __forceinline__ float dot8(uint4 k, f32x4 qa, f32x4 qb) {
    float f0, f1, f2, f3, f4, f5, f6, f7;
    bf2x2(k.x, f0, f1); bf2x2(k.y, f2, f3);
    bf2x2(k.z, f4, f5); bf2x2(k.w, f6, f7);
    return qa.x * f0 + qa.y * f1 + qa.z * f2 + qa.w * f3
         + qb.x * f4 + qb.y * f5 + qb.z * f6 + qb.w * f7;
}

// o[0..7] += w * unpack(v)
__device__ __forceinline__ void acc8(uint4 v, float w, float* o) {
    float f0, f1, f2, f3, f4, f5, f6, f7;
    bf2x2(v.x, f0, f1); bf2x2(v.y, f2, f3);
    bf2x2(v.z, f4, f5); bf2x2(v.w, f6, f7);
    o[0] += w * f0; o[1] += w * f1; o[2] += w * f2; o[3] += w * f3;
    o[4] += w * f4; o[5] += w * f5; o[6] += w * f6; o[7] += w * f7;
}

// ---------------------------------------------------------------------------
// cast body: fp32 -> bf16, 8 elem/thread. Linear block id selects tensor.
// ---------------------------------------------------------------------------
__device__ __forceinline__ void cast_body(int cid,
                                          const float* __restrict__ x,
                                          const float* __restrict__ wq,
                                          const float* __restrict__ wk,
                                          const float* __restrict__ wv,
                                          bf16_t* __restrict__ xb,
                                          bf16_t* __restrict__ wqb,
                                          bf16_t* __restrict__ wkb,
                                          bf16_t* __restrict__ wvb) {
    int z, blk;
    if (cid < 2048) { z = 0; blk = cid; }
    else { int d = cid - 2048; z = 1 + (d >> 7); blk = d & 127; }
    const float* src = (z == 0) ? x : (z == 1) ? wq : (z == 2) ? wk : wv;
    bf16_t* dst      = (z == 0) ? xb : (z == 1) ? wqb : (z == 2) ? wkb : wvb;
    size_t idx = (size_t)blk * 256 + threadIdx.x;
    const float4 a = ((const float4*)src)[idx * 2 + 0];
    const float4 b = ((const float4*)src)[idx * 2 + 1];
    uint4 o;
    o.x = (u32)f2bf(a.x) | ((u32)f2bf(a.y) << 16);
    o.y = (u32)f2bf(a.z) | ((u32)f2bf(a.w) << 16);
    o.z = (u32)f2bf(b.x) | ((u32)f2bf(b.y) << 16);
    o.w = (u32)f2bf(b.z) | ((u32)f2bf(b.w) << 16);
    ((uint4*)dst)[idx] = o;
}

// ---------------------------------------------------------------------------
// xpart body: per-(batch,chunk) partial column-mean of x -> xpart slot.
// ---------------------------------------------------------------------------
__device__ __forceinline__ void xpart_body(int id, const float* __restrict__ x,
                                           float* __restrict__ xpart) {
    const int b = id >> 5, chunk = id & 31;
    const int tid = threadIdx.x;
    const float* xp = x + (size_t)b * SF + (size_t)chunk * 64 * FDIM;
    float s0 = 0.f, s1 = 0.f;
    for (int r = 0; r < 64; ++r) {
        s0 += xp[(size_t)r * FDIM + tid];
        s1 += xp[(size_t)r * FDIM + tid + 256];
    }
    float* dst = xpart + (size_t)id * FDIM;
    dst[tid]       = s0 * (1.f / 2048.f);
    dst[tid + 256] = s1 * (1.f / 2048.f);
}

// ---------------------------------------------------------------------------
// kNN body (HW-validated r14 BLOCK version): exact SET selection via
// two-level histogram. 256 threads, 8 candidates/thread, 6 barriers.
// ---------------------------------------------------------------------------
__device__ __forceinline__ void knn_body(char* smem, int blk,
                                         const float* __restrict__ coords,
                                         u16* __restrict__ nn_out) {
    u32* chist = (u32*)smem;                  // 64  u32
    u32* fhist = (u32*)(smem + 256);          // 256 u32
    u64* bk    = (u64*)(smem + 1280);         // 64  u64
    u64* wpart = (u64*)(smem + 1792);         // 4   u64
    u32* sc    = (u32*)(smem + 1824);         // 8   u32
    const int b   = blk >> 11;
    const int qi  = blk & (SEQ - 1);
    const int t   = threadIdx.x;
    const int wid = t >> 6, lane = t & 63;
    const size_t qb = (size_t)blk * KNN;

    fhist[t & 255] = 0;
    if (t < 64) chist[t] = 0;
    if (t == 0) { sc[2] = 0; sc[3] = 0; }

    const float* cb = coords + (size_t)b * SEQ * 3;
    const float qx = cb[qi * 3 + 0];
    const float qy = cb[qi * 3 + 1];
    const float qz = cb[qi * 3 + 2];

    float dist[8];
    int   ib[8];
    u64 tmin = ~0ull;
#pragma unroll
    for (int i = 0; i < 8; ++i) {
        int c = i * 256 + t;
        float dx = __fsub_rn(cb[c * 3 + 0], qx);
        float dy = __fsub_rn(cb[c * 3 + 1], qy);
        float dz = __fsub_rn(cb[c * 3 + 2], qz);
        // numpy order: (dx*dx + dy*dy) + dz*dz, no FMA, IEEE sqrt
        float d2 = __fadd_rn(__fadd_rn(__fmul_rn(dx, dx), __fmul_rn(dy, dy)),
                             __fmul_rn(dz, dz));
        dist[i] = __fsqrt_rn(d2);
        ib[i] = (int)(dist[i] * 8192.0f);
        u64 key = (((u64)__float_as_uint(dist[i])) << 32) | (u32)c;
        tmin = min_u64(tmin, key);
    }
    tmin = min_u64(tmin, shfl_xor_u64(tmin, 1));
    tmin = min_u64(tmin, shfl_xor_u64(tmin, 2));
    tmin = min_u64(tmin, shfl_xor_u64(tmin, 4));
    tmin = min_u64(tmin, shfl_xor_u64(tmin, 8));
    tmin = min_u64(tmin, shfl_xor_u64(tmin, 16));
    tmin = min_u64(tmin, shfl_xor_u64(tmin, 32));
    if (lane == 0) wpart[wid] = tmin;
    __syncthreads();                                  // B1

#pragma unroll
    for (int i = 0; i < 8; ++i) atomicAdd(&chist[ib[i] >> 8], 1u);
    const u64 M = min_u64(min_u64(wpart[0], wpart[1]),
                          min_u64(wpart[2], wpart[3]));
    __syncthreads();                                  // B2

    if (t < 64) {
        u32 h = chist[t];
        u32 cum = h;
#pragma unroll
        for (int d = 1; d < 64; d <<= 1) {
            u32 v = (u32)__shfl_up((int)cum, d, 64);
            if (t >= d) cum += v;
        }
        u64 bal = __ballot(cum >= 33);
        int Bc = __ffsll((long long)bal) - 1;
        u32 excl = cum - h;
        u32 base = (u32)__shfl((int)excl, Bc, 64);
        if (t == 0) { sc[0] = (u32)Bc; sc[1] = base; }
    }
    __syncthreads();                                  // B3

    {
        const int Bc = (int)sc[0];
#pragma unroll
        for (int i = 0; i < 8; ++i)
            if ((ib[i] >> 8) == Bc) atomicAdd(&fhist[ib[i] & 255], 1u);
    }
    __syncthreads();                                  // B4

    if (t < 64) {
        const u32 Bc = sc[0], base = sc[1];
        u32 f0 = fhist[t * 4 + 0], f1 = fhist[t * 4 + 1];
        u32 f2 = fhist[t * 4 + 2], f3 = fhist[t * 4 + 3];
        u32 s = f0 + f1 + f2 + f3;
        u32 cum = s;
#pragma unroll
        for (int d = 1; d < 64; d <<= 1) {
            u32 v = (u32)__shfl_up((int)cum, d, 64);
            if (t >= d) cum += v;
        }
        u32 E = base + (cum - s);
        u32 c0 = E + f0, c1 = c0 + f1, c2 = c1 + f2, c3 = c2 + f3;
        u64 bal = __ballot(c3 >= 33);
        int L = __ffsll((long long)bal) - 1;
        if (t == L) {
            int j = (c0 >= 33) ? 0 : (c1 >= 33) ? 1 : (c2 >= 33) ? 2 : 3;
            sc[4] = (Bc << 8) | (u32)(t * 4 + j);     // IBT
        }
    }
    __syncthreads();                                  // B5

    {
        const int ibt = (int)sc[4];
#pragma unroll
        for (int i = 0; i < 8; ++i) {
            int c = i * 256 + t;
            u64 key = (((u64)__float_as_uint(dist[i])) << 32) | (u32)c;
            if (ib[i] < ibt) {
                if (key != M) {
                    u32 pos = atomicAdd(&sc[2], 1u);
                    nn_out[qb + pos] = (u16)c;
                }
            } else if (ib[i] == ibt) {
                u32 bp = atomicAdd(&sc[3], 1u);
                if (bp < 64) bk[bp] = key;
            }
        }
    }
    __syncthreads();                                  // B6

    if (t < 64) {
        const u32 m = sc[2];
        const int n = (int)min(sc[3], 64u);
        const int need = 32 - (int)m;
        u64 k = (t < n) ? bk[t] : ~0ull;
        if (k == M) k = ~0ull;
#pragma unroll 1
        for (int r = 0; r < need; ++r) {
            u64 g = k;
            g = min_u64(g, shfl_xor_u64(g, 1));
            g = min_u64(g, shfl_xor_u64(g, 2));
            g = min_u64(g, shfl_xor_u64(g, 4));
            g = min_u64(g, shfl_xor_u64(g, 8));
            g = min_u64(g, shfl_xor_u64(g, 16));
            g = min_u64(g, shfl_xor_u64(g, 32));
            if (k == g) {
                nn_out[qb + m + r] = (u16)(g & 0x7FF);
                k = ~0ull;
            }
        }
    }
}

// ---------------------------------------------------------------------------
// Dispatch 1: cast + xpart + knn, INTERLEAVED (r10-validated).
// ---------------------------------------------------------------------------
__global__ __launch_bounds__(256) void fused_ck(const float* __restrict__ x,
                                                const float* __restrict__ wq,
                                                const float* __restrict__ wk,
                                                const float* __restrict__ wv,
                                                bf16_t* __restrict__ xb,
                                                bf16_t* __restrict__ wqb,
                                                bf16_t* __restrict__ wkb,
                                                bf16_t* __restrict__ wvb,
                                                const float* __restrict__ coords,
                                                u16* __restrict__ nn_out,
                                                float* __restrict__ xpart) {
    __shared__ __align__(16) char smem[1856];   // knn scratch only
    const int bid = blockIdx.x;
    const int g = bid / 21, r = bid - g * 21;
    if (r < 5) {
        const int a = g * 5 + r;                // 0..2559
        if (a < CAST_NB) cast_body(a, x, wq, wk, wv, xb, wqb, wkb, wvb);
        else             xpart_body(a - CAST_NB, x, xpart);
    } else {
        knn_body(smem, g * 16 + (r - 5), coords, nn_out);
    }
}

// ---------------------------------------------------------------------------
// Dispatch 2: GEMM + metric tail (z==3). REVERTED to r10 single-buffer
// (r11 dbuf was neutral — drain-everything barrier limits both forms; keep
// the simpler 16 KB-LDS version).
// ---------------------------------------------------------------------------
__global__ __launch_bounds__(256) void gemm_mfma(const bf16_t* __restrict__ xb,
                                                 const bf16_t* __restrict__ wqb,
                                                 const bf16_t* __restrict__ wkb,
                                                 const bf16_t* __restrict__ wvb,
                                                 bf16_t* __restrict__ qkv,
                                                 const float* __restrict__ xpart,
                                                 const float* __restrict__ Wkf,
                                                 float* __restrict__ metric) {
    __shared__ __align__(16) bf16_t As[128 * 32];
    __shared__ __align__(16) bf16_t Bs[128 * 32];
    const int z = blockIdx.z;
    const int tid  = threadIdx.x;

    if (z == 3) {                         // ---- metric tail ----
        const int id = blockIdx.y * 4 + blockIdx.x;    // 0..255
        if (id >= 8) return;
        float* xbarL = (float*)As;
        const int b = id >> 1;
        float a0 = 0.f, a1 = 0.f;
#pragma unroll 4
        for (int c = 0; c < 32; ++c) {
            const float* xp = xpart + (size_t)((b << 5) | c) * FDIM;
            a0 += xp[tid];
            a1 += xp[tid + 256];
        }
        xbarL[tid] = a0; xbarL[tid + 256] = a1;
        __syncthreads();
        const int f = ((id & 1) << 8) | tid;
        const float* wr = Wkf + (size_t)f * FDIM;
        float acc = 0.f;
#pragma unroll 4
        for (int kk = 0; kk < FDIM; kk += 4) {
            float4 wv = *(const float4*)(wr + kk);
            acc += xbarL[kk + 0] * wv.x + xbarL[kk + 1] * wv.y
                 + xbarL[kk + 2] * wv.z + xbarL[kk + 3] * wv.w;
        }
        metric[(b << 9) | f] = acc;
        return;
    }

    // z: 0 -> Q (slab 2), 1 -> K (slab 0), 2 -> V (slab 1)
    const bf16_t* W = (z == 0) ? wqb : (z == 1) ? wkb : wvb;
    const int slab  = (z == 0) ? 2 : (z - 1);
    const int wid  = tid >> 6, lane = tid & 63;
    const int m16  = lane & 15, quad = lane >> 4;
    const int wm   = (wid & 1) * 64;
    const int wn   = (wid >> 1) * 64;
    const int m0   = blockIdx.y * 128;
    const int n0   = blockIdx.x * 128;

    const int sr = tid >> 2, sc = (tid & 3) * 8;
    const bf16_t* agp = xb + (size_t)(m0 + sr) * FDIM + sc;
    const bf16_t* bgp = W  + (size_t)(n0 + sr) * FDIM + sc;
    bf16_t* lAs = As + tid * 8;          // byte offset tid*16 (linear)
    bf16_t* lBs = Bs + tid * 8;

    f32x4 acc[4][4];
#pragma unroll
    for (int i = 0; i < 4; ++i)
#pragma unroll
        for (int j = 0; j < 4; ++j) acc[i][j] = (f32x4){0.f, 0.f, 0.f, 0.f};

#pragma unroll 1
    for (int k0 = 0; k0 < FDIM; k0 += 32) {
        __syncthreads();                 // prev compute done; LDS reusable
        gld16(agp + k0,                      lAs);
        gld16(agp + (size_t)64 * FDIM + k0,  lAs + 2048);
        gld16(bgp + k0,                      lBs);
        gld16(bgp + (size_t)64 * FDIM + k0,  lBs + 2048);
        __asm__ volatile("s_waitcnt vmcnt(0)" ::: "memory");
        __syncthreads();

        short8 af[4], bfr[4];
#pragma unroll
        for (int i = 0; i < 4; ++i)
            af[i] = *(const short8*)(As + (wm + i * 16 + m16) * 32 + quad * 8);
#pragma unroll
        for (int j = 0; j < 4; ++j)
            bfr[j] = *(const short8*)(Bs + (wn + j * 16 + m16) * 32 + quad * 8);
#pragma unroll
        for (int i = 0; i < 4; ++i)
#pragma unroll
            for (int j = 0; j < 4; ++j)
                acc[i][j] = __builtin_amdgcn_mfma_f32_16x16x32_bf16(af[i], bfr[j],
                                                                    acc[i][j], 0, 0, 0);
    }

    bf16_t* base = qkv + (size_t)slab * BSF;
#pragma unroll
    for (int i = 0; i < 4; ++i) {
        const int rowb = m0 + wm + i * 16 + quad * 4;
#pragma unroll
        for (int r = 0; r < 4; ++r) {
            bf16_t* orow = base + (size_t)(rowb + r) * FDIM + n0 + wn + m16;
            orow[ 0] = f2bf(acc[i][0][r]); orow[16] = f2bf(acc[i][1][r]);
            orow[32] = f2bf(acc[i][2][r]); orow[48] = f2bf(acc[i][3][r]);
        }
    }
}

// ---------------------------------------------------------------------------
// Dispatch 3: Attention v8 — NEW (r12): XCD-L2-resident mapping. Block's
// low 3 bits (which select the XCD via the dispatcher's round-robin) now pin
// (batch, head-half): each XCD touches only 4 heads x 512 KB = 2 MB of K+V,
// fitting its 4 MB private L2 (was: whole-batch 8 MB -> L3-BW-bound at
// ~15.5 TB/s). All 4 waves of a block share ONE query (qi=i>>3), one head
// each (h = hg*4+wid) -> nn row L1-shared.
// ---------------------------------------------------------------------------
__global__ __launch_bounds__(256, 8) void attn_kernel(const bf16_t* __restrict__ qkv,
                                                      const u16* __restrict__ nn,
                                                      float* __restrict__ out) {
    __shared__ float osl[4][8][64];                       // 8 KB: o partials
    const int i   = blockIdx.x;                           // 0..16383
    const int b   = (i & 7) >> 1;                         // XCD -> batch
    const int hg  = i & 1;                                // XCD -> head-half
    const int qi  = i >> 3;                               // 0..2047
    const int tid = threadIdx.x;
    const int wid = tid >> 6, lane = tid & 63;
    const int h   = (hg << 2) | wid;                      // head 0..7
    const int blk = (b << 11) | qi;

    int sreg = 0;
    if (lane < KNN) sreg = (int)nn[(size_t)blk * KNN + lane] & (SEQ - 1);

    const int g3 = lane >> 3, l8 = lane & 7;
    const int r0 = __shfl(sreg,      g3, 64);
    const int r1 = __shfl(sreg,  8 + g3, 64);
    const int r2 = __shfl(sreg, 16 + g3, 64);
    const int r3 = __shfl(sreg, 24 + g3, 64);

    // q: bf16 slab 2, this lane's 8 dims (uniform across g3 -> L1 broadcast)
    const uint4 qw = *(const uint4*)(qkv + 2 * BSF + (size_t)blk * FDIM
                                     + h * HDIM + l8 * 8);

    const bf16_t* base = qkv + ((size_t)(b << 11)) * FDIM + h * HDIM + l8 * 8;
    const uint4 k0 = *(const uint4*)(base + (size_t)r0 * FDIM);
    const uint4 k1 = *(const uint4*)(base + (size_t)r1 * FDIM);
    const uint4 k2 = *(const uint4*)(base + (size_t)r2 * FDIM);
    const uint4 k3 = *(const uint4*)(base + (size_t)r3 * FDIM);
    const uint4 v0 = *(const uint4*)(base + BSF + (size_t)r0 * FDIM);
    const uint4 v1 = *(const uint4*)(base + BSF + (size_t)r1 * FDIM);
    const uint4 v2 = *(const uint4*)(base + BSF + (size_t)r2 * FDIM);
    const uint4 v3 = *(const uint4*)(base + BSF + (size_t)r3 * FDIM);

    float q0, q1, q2, q3, q4, q5, q6, q7;
    bf2x2(qw.x, q0, q1); bf2x2(qw.y, q2, q3);
    bf2x2(qw.z, q4, q5); bf2x2(qw.w, q6, q7);
    const f32x4 qa = {q0, q1, q2, q3};
    const f32x4 qb = {q4, q5, q6, q7};

    // QK^T: per-lane partial dot (8 dims), then 3-step DPP tree over the
    // 8-lane group -> s uniform across the group.
    float s0 = dot8(k0, qa, qb);
    float s1 = dot8(k1, qa, qb);
    float s2 = dot8(k2, qa, qb);
    float s3 = dot8(k3, qa, qb);
    s0 += dppf<0xB1>(s0); s0 += dppf<0x4E>(s0); s0 += dppf<0x141>(s0);
    s1 += dppf<0xB1>(s1); s1 += dppf<0x4E>(s1); s1 += dppf<0x141>(s1);
    s2 += dppf<0xB1>(s2); s2 += dppf<0x4E>(s2); s2 += dppf<0x141>(s2);
    s3 += dppf<0xB1>(s3); s3 += dppf<0x4E>(s3); s3 += dppf<0x141>(s3);
    s0 *= 0.125f; s1 *= 0.125f; s2 *= 0.125f; s3 *= 0.125f;   // 1/sqrt(64)

    // softmax over 32 rows: per-lane 4 values, uniform within 8-groups.
    float ml = fmaxf(fmaxf(s0, s1), fmaxf(s2, s3));
    ml = fmaxf(ml, dppf<0x140>(ml));              // bit3 (uniform-in-8 safe)
    ml = fmaxf(ml, __shfl_xor(ml, 16, 64));
    ml = fmaxf(ml, __shfl_xor(ml, 32, 64));
    const float e0 = __expf(s0 - ml), e1 = __expf(s1 - ml);
    const float e2 = __expf(s2 - ml), e3 = __expf(s3 - ml);
    float sl = (e0 + e1) + (e2 + e3);
    sl += dppf<0x140>(sl);
    sl += __shfl_xor(sl, 16, 64);
    sl += __shfl_xor(sl, 32, 64);
    const float rs = 1.0f / sl;
    const float w0 = e0 * rs, w1 = e1 * rs, w2 = e2 * rs, w3 = e3 * rs;

    // PV: weights lane-local, V rows identical to K rows.
    float o[8] = {0.f, 0.f, 0.f, 0.f, 0.f, 0.f, 0.f, 0.f};
    acc8(v0, w0, o);
    acc8(v1, w1, o);
    acc8(v2, w2, o);
    acc8(v3, w3, o);

    // cross-group reduce (8 groups) via LDS, then coalesced store.
    *(f32x4*)&osl[wid][g3][l8 * 8]     = (f32x4){o[0], o[1], o[2], o[3]};
    *(f32x4*)&osl[wid][g3][l8 * 8 + 4] = (f32x4){o[4], o[5], o[6], o[7]};
    __asm__ volatile("s_waitcnt lgkmcnt(0)" ::: "memory");
    __builtin_amdgcn_wave_barrier();
    float r = osl[wid][0][lane];
#pragma unroll
    for (int g = 1; g < 8; ++g) r += osl[wid][g][lane];
    out[(size_t)blk * FDIM + h * HDIM + lane] = r;
}

// ---------------------------------------------------------------------------
extern "C" void kernel_launch(void* const* d_in, const int* in_sizes, int n_in,
                              void* d_out, int out_size, void* d_ws, size_t ws_size,
                              hipStream_t stream) {
    const float* x      = (const float*)d_in[0];
    const float* coords = (const float*)d_in[1];
    const float* Wq     = (const float*)d_in[2];
    const float* Wk     = (const float*)d_in[3];
    const float* Wv     = (const float*)d_in[4];
    float* out    = (float*)d_out;
    float* metric = out + BSF;

    // ws layout (~34.3 MiB):
    //   xb bf16 BSF (8 MiB) | wqb/wkb/wvb bf16 (1.5 MiB) | qkv bf16 3*BSF
    //   (24 MiB: K,V,Q slabs) | nn u16 (0.5 MiB) | xpart f32 (256 KiB)
    char* p = (char*)d_ws;
    bf16_t* xb    = (bf16_t*)p;                      p += BSF * sizeof(bf16_t);
    bf16_t* wqb   = (bf16_t*)p;                      p += (size_t)FDIM * FDIM * sizeof(bf16_t);
    bf16_t* wkb   = (bf16_t*)p;                      p += (size_t)FDIM * FDIM * sizeof(bf16_t);
    bf16_t* wvb   = (bf16_t*)p;                      p += (size_t)FDIM * FDIM * sizeof(bf16_t);
    bf16_t* qkv   = (bf16_t*)p;                      p += 3 * BSF * sizeof(bf16_t);
    u16*    nn    = (u16*)p;                         p += (size_t)BATCH * SEQ * KNN * sizeof(u16);
    float*  xpart = (float*)p;

    // 1) cast + xpart + knn, interleaved
    fused_ck<<<FUSED_NB, 256, 0, stream>>>(
        x, Wq, Wk, Wv, xb, wqb, wkb, wvb, coords, nn, xpart);

    // 2) gemm (q/k/v -> ws bf16 slabs) + metric tail (z==3)
    gemm_mfma<<<dim3(FDIM / 128, (BATCH * SEQ) / 128, 4), 256, 0, stream>>>(
        xb, wqb, wkb, wvb, qkv, xpart, Wk, metric);

    // 3) attention (XCD-L2-resident mapping)
    attn_kernel<<<BATCH * SEQ * NHEAD / 4, 256, 0, stream>>>(qkv, nn, out);
}